// Round 1
// baseline (4165.126 us; speedup 1.0000x reference)
//
#include <hip/hip_runtime.h>
#include <cstdint>

// Problem dims
#define TB 64
#define TT 256
#define TS 512
#define TE 512
#define TH 1024
#define TV 2048
#define TL 6
#define TPAD 258  // TT + 2 (causal pad)

#define SCALE 0.70710678118654752440f

typedef __attribute__((ext_vector_type(8))) short bf16x8;
typedef __attribute__((ext_vector_type(4))) float f32x4;

__device__ inline unsigned short f2bf(float f) {
  union { float f; unsigned u; } x; x.f = f;
  unsigned r = x.u + 0x7fffu + ((x.u >> 16) & 1u);
  return (unsigned short)(r >> 16);
}

__device__ inline void load16_lds(const void* g, void* l) {
  __builtin_amdgcn_global_load_lds(
      (__attribute__((address_space(1))) void*)const_cast<void*>(g),
      (__attribute__((address_space(3))) void*)l, 16, 0, 0);
}

// ---------------------------------------------------------------------------
// NT GEMM: C[M,N] = A[M,K] @ Bt[N,K]^T (+bias). bf16 inputs, f32 accum.
// M fixed at 16384 = 64 batches * 256 rows; m-tiles (128) never cross a batch.
// A row index = b*sAb + t + rOff (sAb=258 for im2col conv input xpad).
// B row index = b*sBb + n (sBb=512 for per-batch encoder operands, 0=shared).
// ---------------------------------------------------------------------------
__global__ __launch_bounds__(256) void gemm_nt(
    const unsigned short* __restrict__ A,
    const unsigned short* __restrict__ Bt,
    const float* __restrict__ bias,
    float* __restrict__ Cf,
    unsigned short* __restrict__ Cb,
    int N, int K, int lda, int ldb,
    int sAb, int rOff, int sBb)
{
  __shared__ unsigned short ldsA[128 * 64];
  __shared__ unsigned short ldsB[128 * 64];
  const int n0 = blockIdx.x * 128;
  const int m0 = blockIdx.y * 128;
  const int b  = m0 >> 8;       // T = 256
  const int t0 = m0 & 255;
  const unsigned short* Abase = A + ((size_t)b * sAb + t0 + rOff) * lda;
  const unsigned short* Bbase = Bt + ((size_t)b * sBb + n0) * ldb;

  const int tid = threadIdx.x;
  const int wave = tid >> 6, lane = tid & 63;
  const int wm = wave >> 1, wn = wave & 1;  // 2x2 waves of 64x64
  const int lrow = lane >> 3;               // 0..7
  const int lcol = (lane & 7) * 8;          // 8 bf16 = 16B

  f32x4 acc[4][4];
#pragma unroll
  for (int i = 0; i < 4; ++i)
#pragma unroll
    for (int j = 0; j < 4; ++j) acc[i][j] = (f32x4){0.f, 0.f, 0.f, 0.f};

  for (int k0 = 0; k0 < K; k0 += 64) {
#pragma unroll
    for (int it = 0; it < 4; ++it) {
      const int chunk = it * 4 + wave;   // wave-uniform
      const int row = chunk * 8 + lrow;
      load16_lds(Abase + (size_t)row * lda + k0 + lcol, &ldsA[chunk * 512]);
      load16_lds(Bbase + (size_t)row * ldb + k0 + lcol, &ldsB[chunk * 512]);
    }
    __syncthreads();
#pragma unroll
    for (int kk = 0; kk < 2; ++kk) {
      const int kb = kk * 32 + (lane >> 4) * 8;
      bf16x8 af[4], bfr[4];
#pragma unroll
      for (int f = 0; f < 4; ++f) {
        af[f]  = *(const bf16x8*)&ldsA[(wm * 64 + f * 16 + (lane & 15)) * 64 + kb];
        bfr[f] = *(const bf16x8*)&ldsB[(wn * 64 + f * 16 + (lane & 15)) * 64 + kb];
      }
#pragma unroll
      for (int mi = 0; mi < 4; ++mi)
#pragma unroll
        for (int ni = 0; ni < 4; ++ni)
          acc[mi][ni] = __builtin_amdgcn_mfma_f32_16x16x32_bf16(
              af[mi], bfr[ni], acc[mi][ni], 0, 0, 0);
    }
    __syncthreads();
  }

  const int cr = (lane >> 4) * 4;
  const int cc = lane & 15;
#pragma unroll
  for (int mi = 0; mi < 4; ++mi) {
#pragma unroll
    for (int j = 0; j < 4; ++j) {
      const int m = m0 + wm * 64 + mi * 16 + cr + j;
#pragma unroll
      for (int ni = 0; ni < 4; ++ni) {
        const int n = n0 + wn * 64 + ni * 16 + cc;
        float v = acc[mi][ni][j];
        if (bias) v += bias[n];
        if (Cf) Cf[(size_t)m * N + n] = v;
        if (Cb) Cb[(size_t)m * N + n] = f2bf(v);
      }
    }
  }
}

// ---------------------------------------------------------------------------
// Converters / elementwise
// ---------------------------------------------------------------------------
__global__ __launch_bounds__(256) void transpose_bf16(
    const float* __restrict__ in, unsigned short* __restrict__ out,
    int R, int C, size_t inBatch, size_t outBatch)
{
  __shared__ float tile[32][33];
  const float* ip = in + blockIdx.z * inBatch;
  unsigned short* op = out + blockIdx.z * outBatch;
  const int c0 = blockIdx.x * 32, r0 = blockIdx.y * 32;
  const int tx = threadIdx.x & 31, ty = threadIdx.x >> 5;
#pragma unroll
  for (int i = 0; i < 32; i += 8)
    tile[ty + i][tx] = ip[(size_t)(r0 + ty + i) * C + c0 + tx];
  __syncthreads();
#pragma unroll
  for (int i = 0; i < 32; i += 8)
    op[(size_t)(c0 + ty + i) * R + r0 + tx] = f2bf(tile[tx][ty + i]);
}

__global__ void cvt_bf16(const float* __restrict__ in, unsigned short* __restrict__ out, size_t n) {
  size_t i = ((size_t)blockIdx.x * 256 + threadIdx.x) * 4;
  if (i >= n) return;
  float4 v = *(const float4*)(in + i);
  ushort4 o; o.x = f2bf(v.x); o.y = f2bf(v.y); o.z = f2bf(v.z); o.w = f2bf(v.w);
  *(ushort4*)(out + i) = o;
}

// conv_w [L,2H,H,3] -> Bt layout [l][oc][j*H+ic] bf16
__global__ void convw_t_k(const float* __restrict__ w, unsigned short* __restrict__ wt) {
  size_t i = (size_t)blockIdx.x * 256 + threadIdx.x;  // over 6*2048*3072
  int kk = (int)(i % 3072);
  size_t q = i / 3072;             // l*2048 + oc
  int j = kk >> 10, ic = kk & 1023;
  wt[i] = f2bf(w[(q * 1024 + ic) * 3 + j]);
}

__global__ void embed_k(const int* __restrict__ trg, const float* __restrict__ tok,
                        const float* __restrict__ pos, float* __restrict__ emb,
                        unsigned short* __restrict__ embb) {
  int bt = blockIdx.x;             // b*T + t
  int t = bt & 255, b = bt >> 8;
  int tk = trg[t * TB + b];        // trg is [T,B]
  int e = threadIdx.x * 2;
  float2 tv = *(const float2*)(tok + (size_t)tk * TE + e);
  float2 pv = *(const float2*)(pos + (size_t)t * TE + e);
  float2 r; r.x = tv.x + pv.x; r.y = tv.y + pv.y;
  size_t o = (size_t)bt * TE + e;
  *(float2*)(emb + o) = r;
  ushort2 ob; ob.x = f2bf(r.x); ob.y = f2bf(r.y);
  *(ushort2*)(embb + o) = ob;
}

__global__ void xpad_k(const float* __restrict__ x, unsigned short* __restrict__ xpad) {
  int idx = blockIdx.x;            // b*258 + tau
  int tau = idx % TPAD, b = idx / TPAD;
  int e = threadIdx.x * 4;
  ushort4 o;
  if (tau < 2) { o.x = o.y = o.z = o.w = 0; }
  else {
    float4 v = *(const float4*)(x + ((size_t)(b * TT + tau - 2) * TH + e));
    o.x = f2bf(v.x); o.y = f2bf(v.y); o.z = f2bf(v.z); o.w = f2bf(v.w);
  }
  *(ushort4*)(xpad + (size_t)idx * TH + e) = o;
}

__global__ void glu_k(const float* __restrict__ pre, float* __restrict__ cv,
                      unsigned short* __restrict__ cvb) {
  int m = blockIdx.x;
  int c = threadIdx.x * 4;
  float4 a = *(const float4*)(pre + (size_t)m * 2048 + c);
  float4 g = *(const float4*)(pre + (size_t)m * 2048 + 1024 + c);
  float4 r;
  r.x = a.x / (1.f + __expf(-g.x));
  r.y = a.y / (1.f + __expf(-g.y));
  r.z = a.z / (1.f + __expf(-g.z));
  r.w = a.w / (1.f + __expf(-g.w));
  size_t o = (size_t)m * TH + c;
  *(float4*)(cv + o) = r;
  ushort4 ob; ob.x = f2bf(r.x); ob.y = f2bf(r.y); ob.z = f2bf(r.z); ob.w = f2bf(r.w);
  *(ushort4*)(cvb + o) = ob;
}

__global__ void combined_k(const float* __restrict__ ce, const float* __restrict__ emb,
                           unsigned short* __restrict__ out) {
  size_t i = ((size_t)blockIdx.x * 256 + threadIdx.x) * 4;
  float4 a = *(const float4*)(ce + i);
  float4 b = *(const float4*)(emb + i);
  ushort4 o;
  o.x = f2bf((a.x + b.x) * SCALE); o.y = f2bf((a.y + b.y) * SCALE);
  o.z = f2bf((a.z + b.z) * SCALE); o.w = f2bf((a.w + b.w) * SCALE);
  *(ushort4*)(out + i) = o;
}

__global__ __launch_bounds__(256) void softmax_k(const float* __restrict__ energy,
                                                 unsigned short* __restrict__ ab,
                                                 float* __restrict__ af) {
  int row = blockIdx.x * 4 + (threadIdx.x >> 6);  // one wave per row of 512
  int lane = threadIdx.x & 63;
  const float* e = energy + (size_t)row * TS;
  float4 v0 = *(const float4*)(e + lane * 4);
  float4 v1 = *(const float4*)(e + 256 + lane * 4);
  float mx = fmaxf(fmaxf(fmaxf(v0.x, v0.y), fmaxf(v0.z, v0.w)),
                   fmaxf(fmaxf(v1.x, v1.y), fmaxf(v1.z, v1.w)));
#pragma unroll
  for (int d = 1; d < 64; d <<= 1) mx = fmaxf(mx, __shfl_xor(mx, d));
  v0.x = __expf(v0.x - mx); v0.y = __expf(v0.y - mx);
  v0.z = __expf(v0.z - mx); v0.w = __expf(v0.w - mx);
  v1.x = __expf(v1.x - mx); v1.y = __expf(v1.y - mx);
  v1.z = __expf(v1.z - mx); v1.w = __expf(v1.w - mx);
  float s = v0.x + v0.y + v0.z + v0.w + v1.x + v1.y + v1.z + v1.w;
#pragma unroll
  for (int d = 1; d < 64; d <<= 1) s += __shfl_xor(s, d);
  float inv = 1.f / s;
  v0.x *= inv; v0.y *= inv; v0.z *= inv; v0.w *= inv;
  v1.x *= inv; v1.y *= inv; v1.z *= inv; v1.w *= inv;
  ushort4 o0, o1;
  o0.x = f2bf(v0.x); o0.y = f2bf(v0.y); o0.z = f2bf(v0.z); o0.w = f2bf(v0.w);
  o1.x = f2bf(v1.x); o1.y = f2bf(v1.y); o1.z = f2bf(v1.z); o1.w = f2bf(v1.w);
  size_t o = (size_t)row * TS + lane * 4;
  *(ushort4*)(ab + o) = o0;
  *(ushort4*)(ab + o + 256) = o1;
  if (af) {
    *(float4*)(af + o) = v0;
    *(float4*)(af + o + 256) = v1;
  }
}

__global__ void resid_k(const float* __restrict__ cv, const float* __restrict__ a2,
                        float* __restrict__ x, unsigned short* __restrict__ xpad) {
  int bt = blockIdx.x;
  int b = bt >> 8, t = bt & 255;
  int c = threadIdx.x * 4;
  size_t o = (size_t)bt * TH + c;
  float4 v = *(const float4*)(cv + o);
  float4 w = *(const float4*)(a2 + o);
  float4 xv = *(const float4*)(x + o);
  float4 r;
  r.x = ((v.x + w.x) * SCALE + xv.x) * SCALE;
  r.y = ((v.y + w.y) * SCALE + xv.y) * SCALE;
  r.z = ((v.z + w.z) * SCALE + xv.z) * SCALE;
  r.w = ((v.w + w.w) * SCALE + xv.w) * SCALE;
  *(float4*)(x + o) = r;
  ushort4 ob; ob.x = f2bf(r.x); ob.y = f2bf(r.y); ob.z = f2bf(r.z); ob.w = f2bf(r.w);
  *(ushort4*)(xpad + ((size_t)(b * TPAD + t + 2) * TH + c)) = ob;
}

// ---------------------------------------------------------------------------
extern "C" void kernel_launch(void* const* d_in, const int* in_sizes, int n_in,
                              void* d_out, int out_size, void* d_ws, size_t ws_size,
                              hipStream_t stream) {
  (void)in_sizes; (void)n_in; (void)out_size; (void)ws_size;
  const int*   trg    = (const int*)d_in[0];
  const float* encC   = (const float*)d_in[1];
  const float* encM   = (const float*)d_in[2];
  const float* tokE   = (const float*)d_in[3];
  const float* posE   = (const float*)d_in[4];
  const float* w_e2h  = (const float*)d_in[5];
  const float* b_e2h  = (const float*)d_in[6];
  const float* w_h2e  = (const float*)d_in[7];
  const float* b_h2e  = (const float*)d_in[8];
  const float* w_ah2e = (const float*)d_in[9];
  const float* b_ah2e = (const float*)d_in[10];
  const float* w_ae2h = (const float*)d_in[11];
  const float* b_ae2h = (const float*)d_in[12];
  const float* w_out  = (const float*)d_in[13];
  const float* b_out  = (const float*)d_in[14];
  const float* convW  = (const float*)d_in[15];
  const float* convB  = (const float*)d_in[16];

  char* p = (char*)d_ws;
  auto take = [&](size_t nbytes) {
    char* r = p; p += (nbytes + 255) & ~(size_t)255; return r;
  };
  float* embedded        = (float*)take((size_t)16384 * 512 * 4);
  float* x               = (float*)take((size_t)16384 * 1024 * 4);
  unsigned short* xpad   = (unsigned short*)take((size_t)64 * TPAD * 1024 * 2);
  float* convd           = (float*)take((size_t)16384 * 1024 * 4);
  unsigned short* convd_b= (unsigned short*)take((size_t)16384 * 1024 * 2);
  unsigned short* comb_b = (unsigned short*)take((size_t)16384 * 512 * 2);
  unsigned short* attn_b = (unsigned short*)take((size_t)16384 * 512 * 2);
  unsigned short* attd_b = (unsigned short*)take((size_t)16384 * 512 * 2);
  unsigned short* wt_e2h = (unsigned short*)take((size_t)512 * 1024 * 2);
  unsigned short* wt_h2e = (unsigned short*)take((size_t)1024 * 512 * 2);
  unsigned short* wt_ah2e= (unsigned short*)take((size_t)1024 * 512 * 2);
  unsigned short* wt_ae2h= (unsigned short*)take((size_t)512 * 1024 * 2);
  unsigned short* wt_out = (unsigned short*)take((size_t)512 * 2048 * 2);
  unsigned short* wt_conv= (unsigned short*)take((size_t)6 * 2048 * 3072 * 2);
  unsigned short* encC_b = (unsigned short*)take((size_t)64 * 512 * 512 * 2);
  unsigned short* encM_t = (unsigned short*)take((size_t)64 * 512 * 512 * 2);
  unsigned short* emb_b  = comb_b;  // alias: dead before comb_b first written
  unsigned short* oemb_b = attn_b;  // alias: dead before out_emb written

  // d_out doubles as scratch: the [B,T,V] f32 region is written only by the
  // final GEMM; everything staged in it is dead by then.
  float* outMain = (float*)d_out;                       // [16384, 2048]
  float* outAttn = outMain + (size_t)16384 * 2048;      // [16384, 512]
  float* pre     = outMain;                             // [16384, 2048]
  float* cemb    = outMain;                             // [16384, 512]
  float* energy  = outMain + (size_t)16384 * 512;       // [16384, 512]
  float* att2    = outMain + (size_t)16384 * 1024;      // [16384, 1024]

  // ---- weight / encoder conversions (inputs restored every call) ----
  transpose_bf16<<<dim3(32, 16, 1), 256, 0, stream>>>(w_e2h, wt_e2h, 512, 1024, 0, 0);
  transpose_bf16<<<dim3(16, 32, 1), 256, 0, stream>>>(w_h2e, wt_h2e, 1024, 512, 0, 0);
  transpose_bf16<<<dim3(16, 32, 1), 256, 0, stream>>>(w_ah2e, wt_ah2e, 1024, 512, 0, 0);
  transpose_bf16<<<dim3(32, 16, 1), 256, 0, stream>>>(w_ae2h, wt_ae2h, 512, 1024, 0, 0);
  transpose_bf16<<<dim3(64, 16, 1), 256, 0, stream>>>(w_out, wt_out, 512, 2048, 0, 0);
  transpose_bf16<<<dim3(16, 16, 64), 256, 0, stream>>>(encM, encM_t, 512, 512,
                                                       (size_t)512 * 512, (size_t)512 * 512);
  cvt_bf16<<<16384, 256, 0, stream>>>(encC, encC_b, (size_t)64 * 512 * 512);
  convw_t_k<<<147456, 256, 0, stream>>>(convW, wt_conv);

  // ---- embedding & input projection ----
  embed_k<<<16384, 256, 0, stream>>>(trg, tokE, posE, embedded, emb_b);
  gemm_nt<<<dim3(8, 128), 256, 0, stream>>>(emb_b, wt_e2h, b_e2h, x, nullptr,
                                            1024, 512, 512, 512, 256, 0, 0);
  xpad_k<<<64 * TPAD, 256, 0, stream>>>(x, xpad);

  // ---- decoder layers ----
  for (int i = 0; i < TL; ++i) {
    // causal conv as im2col GEMM: K = 3*H, A rows from xpad (stride H)
    gemm_nt<<<dim3(16, 128), 256, 0, stream>>>(xpad, wt_conv + (size_t)i * 2048 * 3072,
                                               convB + i * 2048, pre, nullptr,
                                               2048, 3072, 1024, 3072, TPAD, 0, 0);
    glu_k<<<16384, 256, 0, stream>>>(pre, convd, convd_b);
    gemm_nt<<<dim3(4, 128), 256, 0, stream>>>(convd_b, wt_ah2e, b_ah2e, cemb, nullptr,
                                              512, 1024, 1024, 1024, 256, 0, 0);
    combined_k<<<8192, 256, 0, stream>>>(cemb, embedded, comb_b);
    gemm_nt<<<dim3(4, 128), 256, 0, stream>>>(comb_b, encC_b, nullptr, energy, nullptr,
                                              512, 512, 512, 512, 256, 0, 512);
    softmax_k<<<4096, 256, 0, stream>>>(energy, attn_b, (i == TL - 1) ? outAttn : nullptr);
    gemm_nt<<<dim3(4, 128), 256, 0, stream>>>(attn_b, encM_t, nullptr, nullptr, attd_b,
                                              512, 512, 512, 512, 256, 0, 512);
    gemm_nt<<<dim3(8, 128), 256, 0, stream>>>(attd_b, wt_ae2h, b_ae2h, att2, nullptr,
                                              1024, 512, 512, 512, 256, 0, 0);
    resid_k<<<16384, 256, 0, stream>>>(convd, att2, x, xpad);
  }

  // ---- output head ----
  gemm_nt<<<dim3(4, 128), 256, 0, stream>>>(xpad, wt_h2e, b_h2e, nullptr, oemb_b,
                                            512, 1024, 1024, 1024, TPAD, 2, 0);
  gemm_nt<<<dim3(16, 128), 256, 0, stream>>>(oemb_b, wt_out, b_out, outMain, nullptr,
                                             2048, 512, 512, 512, 256, 0, 0);
}